// Round 1
// baseline (240.801 us; speedup 1.0000x reference)
//
#include <hip/hip_runtime.h>
#include <math.h>

// ---------------------------------------------------------------------------
// AudioFinder, MFMA v4 — concurrency round.
// 32-row tiles (2x grid, ~6 blocks/CU resident), batched staging loads
// (single vmcnt drain instead of 8 serialized load latencies), separate
// gate buffer (one barrier fewer), FINAL uses gsA/gsB ping-pong (4 syncs).
// Block = 320 thr / 5 waves; wave w owns n-tiles (w, w+5) = the GLU (a,g)
// pair. W streams from global into registers (L2-resident). Weights
// pre-packed bf16 (wide: k'-major; 1x1: K padded 96).
// ---------------------------------------------------------------------------

#define NBATCH 16

typedef __attribute__((ext_vector_type(8))) short s16x8;
typedef __attribute__((ext_vector_type(4))) float f32x4;

__device__ __forceinline__ float fast_sigmoid(float x){ return 1.0f/(1.0f+__expf(-x)); }
__device__ __forceinline__ float fast_tanh(float x){ return 2.0f/(1.0f+__expf(-2.0f*x))-1.0f; }
__device__ __forceinline__ unsigned short f2bf(float f){
    unsigned int u = __float_as_uint(f);
    return (unsigned short)((u + 0x7FFFu + ((u >> 16) & 1u)) >> 16);
}

// ============================================================================
// One-time packs: WW (4,160,320) k'-major; W1/F0/F1 (·,80,96) zero-padded;
// EMB bf16; e2.
// ============================================================================
__global__ __launch_bounds__(256) void pack_all(
    const float* __restrict__ w_wide, const float* __restrict__ w_1x1,
    const float* __restrict__ wf0,    const float* __restrict__ wf1,
    const float* __restrict__ emb,
    unsigned short* __restrict__ WW, unsigned short* __restrict__ W1,
    unsigned short* __restrict__ F0, unsigned short* __restrict__ F1,
    unsigned short* __restrict__ EM, float* __restrict__ e2o)
{
    int i = blockIdx.x * 256 + threadIdx.x;
    if (i < 204800) {
        int l = i / 51200, r = i % 51200, oc = r / 320, k = r % 320;
        int j = k / 80, ic = k % 80;
        WW[i] = f2bf(w_wide[l * 51200 + oc * 320 + ic * 4 + j]);
    } else if (i < 235520) {
        int idx = i - 204800, l = idx / 7680, r = idx % 7680, oc = r / 96, k = r % 96;
        W1[idx] = (k < 80) ? f2bf(w_1x1[l * 6400 + oc * 80 + k]) : (unsigned short)0;
    } else if (i < 243200) {
        int idx = i - 235520, oc = idx / 96, k = idx % 96;
        F0[idx] = (k < 80) ? f2bf(wf0[oc * 80 + k]) : (unsigned short)0;
    } else if (i < 250880) {
        int idx = i - 243200, oc = idx / 96, k = idx % 96;
        F1[idx] = (k < 80) ? f2bf(wf1[oc * 80 + k]) : (unsigned short)0;
    } else if (i < 291840) {
        EM[i - 250880] = f2bf(emb[i - 250880]);
    } else if (i < 292352) {
        int e = i - 291840;
        float s = 0.f;
        for (int k = 0; k < 80; ++k) { float v = emb[e * 80 + k]; s = fmaf(v, v, s); }
        e2o[e] = s;
    }
}

// ============================================================================
// Fused encoder layer v4 (32-row tiles).
// Frag layouts (verified m89/m120): A/B lane: [m|n=lane&15][k=quad*8+j];
// D: col=lane&15 (n), row=quad*4+reg (m).
// ============================================================================
template<int S, bool HAS_RES, bool FINAL>
__global__ __launch_bounds__(320, 6) void enc_layer(
    const float* __restrict__ xS, const float* __restrict__ xQ,
    const unsigned short* __restrict__ ww,  const float* __restrict__ wb,
    const unsigned short* __restrict__ w1p, const float* __restrict__ b1,
    const unsigned short* __restrict__ f0p, const float* __restrict__ bf0,
    const unsigned short* __restrict__ f1p, const float* __restrict__ bf1,
    float* __restrict__ outS, float* __restrict__ outQ,
    int TinS, int ToutS, int TinQ, int ToutQ, int nbS)
{
    constexpr int TILE = 32;
    constexpr int MT   = 2;                          // m-tiles per wave
    constexpr int P    = (TILE - 1) * S + 4;         // 66 / 35 staged rows
    constexpr int HALF = (S == 2) ? (P / 2) : P;     // 33 / 35
    constexpr int NEL  = P * 20;                     // float4 elements staged
    constexpr int NST  = (NEL + 319) / 320;          // 5 / 3 per thread
    constexpr int NPARY = (S == 2) ? 2 : 1;

    __shared__ __attribute__((aligned(16))) unsigned short xs[NPARY * HALF * 88];
    __shared__ __attribute__((aligned(16))) unsigned short gsA[TILE * 104];
    __shared__ __attribute__((aligned(16))) unsigned short gsB[FINAL ? TILE * 104 : 8];

    const int tid  = threadIdx.x;
    const int wave = tid >> 6;                       // 0..4 = n-pair
    const int lane = tid & 63;
    const int m    = lane & 15;
    const int quad = lane >> 4;
    const int n_   = blockIdx.y;

    const float* x; float* out; int T_in, T_out, bx;
    if ((int)blockIdx.x < nbS) { x = xS; out = outS; T_in = TinS; T_out = ToutS; bx = blockIdx.x; }
    else                       { x = xQ; out = outQ; T_in = TinQ; T_out = ToutQ; bx = blockIdx.x - nbS; }
    const int t0 = bx * TILE;
    const long base_in = (long)n_ * T_in * 80;

    // ---- B-frag global pointers (registers, depth-2 pipeline) ----
    const int quad8 = quad * 8;
    const unsigned short* wa_base = ww + (long)(wave * 16 + m) * 320 + quad8;
    const unsigned short* wg_base = ww + (long)((wave + 5) * 16 + m) * 320 + quad8;
    auto ldB = [&](const unsigned short* b, int kk) { return *(const s16x8*)(b + kk * 32); };

    // ---- stage x tile: issue ALL loads first (one latency wall), convert after ----
    float4 vst[NST]; int odx[NST]; bool okw[NST];
#pragma unroll
    for (int it = 0; it < NST; ++it) {
        int u = tid + it * 320;
        okw[it] = (u < NEL);
        if (u >= NEL) u = NEL - 1;
        int pos = u / 20, c4 = u % 20;
        int tp = t0 * S + pos; if (tp > T_in - 1) tp = T_in - 1;
        vst[it] = *(const float4*)(x + base_in + (long)tp * 80 + c4 * 4);
        int row = (S == 2) ? (pos >> 1) : pos;
        int par = (S == 2) ? (pos & 1) : 0;
        odx[it] = (par * HALF + row) * 88 + c4 * 4;
    }

    s16x8 baP[3], bgP[3];
    baP[0] = ldB(wa_base, 0); bgP[0] = ldB(wg_base, 0);
    baP[1] = ldB(wa_base, 1); bgP[1] = ldB(wg_base, 1);

#pragma unroll
    for (int it = 0; it < NST; ++it) {
        if (okw[it]) {
            float4 v = vst[it];
            unsigned int s0 = (unsigned int)f2bf(v.x) | ((unsigned int)f2bf(v.y) << 16);
            unsigned int s1 = (unsigned int)f2bf(v.z) | ((unsigned int)f2bf(v.w) << 16);
            *(uint2*)&xs[odx[it]] = make_uint2(s0, s1);
        }
    }

    f32x4 acc_a[MT], acc_g[MT];
#pragma unroll
    for (int mt = 0; mt < MT; ++mt) {
        acc_a[mt] = (f32x4){0.f, 0.f, 0.f, 0.f};
        acc_g[mt] = (f32x4){0.f, 0.f, 0.f, 0.f};
    }

    __syncthreads();   // xs ready

    // ---- wide conv K-loop: NO barriers ----
#pragma unroll
    for (int kk = 0; kk < 10; ++kk) {
        if (kk + 2 < 10) {
            baP[(kk + 2) % 3] = ldB(wa_base, kk + 2);
            bgP[(kk + 2) % 3] = ldB(wg_base, kk + 2);
        }
        const int kq = kk * 32 + quad8;
        const int j  = (kq >= 240) ? 3 : ((kq >= 160) ? 2 : ((kq >= 80) ? 1 : 0));
        const int ic0 = kq - j * 80;
        int xb;
        if (S == 2) xb = ((j & 1) * HALF + (j >> 1)) * 88 + ic0;
        else        xb = j * 88 + ic0;
        s16x8 a[MT];
#pragma unroll
        for (int mt = 0; mt < MT; ++mt)
            a[mt] = *(const s16x8*)&xs[xb + (mt * 16 + m) * 88];
        s16x8 ba = baP[kk % 3], bg = bgP[kk % 3];
#pragma unroll
        for (int mt = 0; mt < MT; ++mt) {
            acc_a[mt] = __builtin_amdgcn_mfma_f32_16x16x32_bf16(a[mt], ba, acc_a[mt], 0, 0, 0);
            acc_g[mt] = __builtin_amdgcn_mfma_f32_16x16x32_bf16(a[mt], bg, acc_g[mt], 0, 0, 0);
        }
    }

    // ---- gate -> gsA (separate buffer: no barrier needed before writes) ----
    const float ba_b = wb[wave * 16 + m];
    const float bg_b = wb[80 + wave * 16 + m];
#pragma unroll
    for (int mt = 0; mt < MT; ++mt)
#pragma unroll
        for (int r = 0; r < 4; ++r) {
            float av = acc_a[mt][r] + ba_b;
            float gv = acc_g[mt][r] + bg_b;
            gsA[(mt * 16 + quad * 4 + r) * 104 + wave * 16 + m] =
                f2bf(fast_tanh(av) * fast_sigmoid(gv));
        }
    const uint4 z4 = make_uint4(0u, 0u, 0u, 0u);
    {
        constexpr int NPAD = FINAL ? 128 : 64;       // pad cols 80..95 of gsA (and gsB)
        for (int u = tid; u < NPAD; u += 320) {
            unsigned short* g = (u < 64) ? gsA : gsB;
            int v = u & 63;
            *(uint4*)&g[(v >> 1) * 104 + 80 + (v & 1) * 8] = z4;
        }
    }
    __syncthreads();   // gsA (and pads) ready

    // ---- 1x1 (K=96, B zero-padded at pack time) ----
    auto mm96 = [&](const unsigned short* Wp, const unsigned short* g, f32x4 (&o)[MT]) {
        const unsigned short* wb1 = Wp + (long)(wave * 16 + m) * 96 + quad8;
        s16x8 b0  = *(const s16x8*)(wb1);
        s16x8 b1f = *(const s16x8*)(wb1 + 32);
        s16x8 b2  = *(const s16x8*)(wb1 + 64);
#pragma unroll
        for (int mt = 0; mt < MT; ++mt) o[mt] = (f32x4){0.f, 0.f, 0.f, 0.f};
#pragma unroll
        for (int kb = 0; kb < 3; ++kb) {
            s16x8 b = (kb == 0) ? b0 : ((kb == 1) ? b1f : b2);
#pragma unroll
            for (int mt = 0; mt < MT; ++mt) {
                s16x8 ag = *(const s16x8*)&g[(mt * 16 + m) * 104 + kb * 32 + quad8];
                o[mt] = __builtin_amdgcn_mfma_f32_16x16x32_bf16(ag, b, o[mt], 0, 0, 0);
            }
        }
    };

    f32x4 a1[MT];
    mm96(w1p, gsA, a1);

    const long base_out = (long)n_ * T_out * 80;
    const int c = wave * 16 + m;
    if (!FINAL) {
        const float b1c = b1[c];
#pragma unroll
        for (int mt = 0; mt < MT; ++mt)
#pragma unroll
            for (int r = 0; r < 4; ++r) {
                int tg = t0 + mt * 16 + quad * 4 + r;
                if (tg < T_out) {
                    float v = a1[mt][r] + b1c;
                    if (HAS_RES)
                        v += x[base_in + (long)(3 + (long)tg * S) * 80 + c];
                    out[base_out + (long)tg * 80 + c] = v;
                }
            }
    } else {
        const float b1c = b1[c];
        float x3[MT][4];
#pragma unroll
        for (int mt = 0; mt < MT; ++mt)
#pragma unroll
            for (int r = 0; r < 4; ++r) {
                int tg = t0 + mt * 16 + quad * 4 + r;
                int tc = (tg < T_out) ? tg : (T_out - 1);
                float v = a1[mt][r] + b1c;
                if (HAS_RES)
                    v += x[base_in + (long)(3 + (long)tc * S) * 80 + c];
                x3[mt][r] = v;
            }
        // x3 -> gsB (gsB untouched so far; own gsA reads done via a1 dep)
#pragma unroll
        for (int mt = 0; mt < MT; ++mt)
#pragma unroll
            for (int r = 0; r < 4; ++r)
                gsB[(mt * 16 + quad * 4 + r) * 104 + c] = f2bf(x3[mt][r]);
        __syncthreads();   // gsB ready; all waves past their gsA reads
        f32x4 a2[MT];
        mm96(f0p, gsB, a2);
        const float bf0c = bf0[c];
        // relu -> gsA (safe: every wave's gsA reads preceded the barrier above)
#pragma unroll
        for (int mt = 0; mt < MT; ++mt)
#pragma unroll
            for (int r = 0; r < 4; ++r)
                gsA[(mt * 16 + quad * 4 + r) * 104 + c] =
                    f2bf(fmaxf(a2[mt][r] + bf0c, 0.f));
        __syncthreads();   // relu ready
        f32x4 a3[MT];
        mm96(f1p, gsA, a3);
        const float bf1c = bf1[c];
#pragma unroll
        for (int mt = 0; mt < MT; ++mt)
#pragma unroll
            for (int r = 0; r < 4; ++r) {
                int tg = t0 + mt * 16 + quad * 4 + r;
                if (tg < T_out)
                    out[base_out + (long)tg * 80 + c] = a3[mt][r] + bf1c;
            }
    }
}

// ============================================================================
// VQ via bf16 MFMA (unchanged, known-good).
// ============================================================================
__global__ __launch_bounds__(256, 2) void vq_mfma(
    const float* __restrict__ enc_s, const float* __restrict__ enc_q,
    const unsigned short* __restrict__ embp, const float* __restrict__ emb,
    const float* __restrict__ e2v,
    const float* __restrict__ w_lin, const float* __restrict__ b_lin,
    float* __restrict__ pred)
{
    __shared__ unsigned short xs[64 * 104];
    __shared__ unsigned short es[128 * 104];
    const uint4 z4 = make_uint4(0u, 0u, 0u, 0u);

    const int tid  = threadIdx.x;
    const int wave = tid >> 6;
    const int lane = tid & 63;
    const int m    = lane & 15;
    const int quad = lane >> 4;
    const int n    = blockIdx.y;
    const int t0   = blockIdx.x * 64;

    for (int u = tid; u < 64 * 20; u += 256) {
        int row = u / 20, c4 = u % 20;
        int t = t0 + row; if (t > 2039) t = 2039;
        float4 v = *(const float4*)(enc_s + ((long)n * 2040 + t) * 80 + c4 * 4);
        unsigned int s0 = (unsigned int)f2bf(v.x) | ((unsigned int)f2bf(v.y) << 16);
        unsigned int s1 = (unsigned int)f2bf(v.z) | ((unsigned int)f2bf(v.w) << 16);
        *(uint2*)&xs[row * 104 + c4 * 4] = make_uint2(s0, s1);
    }
    for (int u = tid; u < 128; u += 256)
        *(uint4*)&xs[(u >> 1) * 104 + 80 + (u & 1) * 8] = z4;
    __syncthreads();

    s16x8 af[3];
#pragma unroll
    for (int kb = 0; kb < 3; ++kb)
        af[kb] = *(const s16x8*)&xs[(wave * 16 + m) * 104 + kb * 32 + quad * 8];

    float best[4]; int bi[4];
#pragma unroll
    for (int r = 0; r < 4; ++r) { best[r] = 1e30f; bi[r] = 0; }

    for (int ch = 0; ch < 4; ++ch) {
        const int c0 = ch * 128;
        __syncthreads();
        for (int u = tid; u < 128 * 12; u += 256) {
            int el = u / 12, seg = u % 12;
            uint4 v = z4;
            if (seg < 10) v = *(const uint4*)(embp + (long)(c0 + el) * 80 + seg * 8);
            *(uint4*)&es[el * 104 + seg * 8] = v;
        }
        __syncthreads();

        f32x4 acc[8];
#pragma unroll
        for (int nt = 0; nt < 8; ++nt) acc[nt] = (f32x4){0.f, 0.f, 0.f, 0.f};
#pragma unroll
        for (int kb = 0; kb < 3; ++kb) {
            const int k0 = kb * 32 + quad * 8;
#pragma unroll
            for (int nt = 0; nt < 8; ++nt) {
                s16x8 b = *(const s16x8*)&es[(nt * 16 + m) * 104 + k0];
                acc[nt] = __builtin_amdgcn_mfma_f32_16x16x32_bf16(af[kb], b, acc[nt], 0, 0, 0);
            }
        }
#pragma unroll
        for (int nt = 0; nt < 8; ++nt) {
            const int e = c0 + nt * 16 + m;
            const float e2x = e2v[e];
#pragma unroll
            for (int r = 0; r < 4; ++r) {
                float s = fmaf(-2.0f, acc[nt][r], e2x);
                if (s < best[r]) { best[r] = s; bi[r] = e; }
            }
        }
    }

    __syncthreads();
    float* rb = (float*)es;
    int*   ri = (int*)es + 1088;
#pragma unroll
    for (int r = 0; r < 4; ++r) {
        int tl = wave * 16 + quad * 4 + r;
        rb[tl * 17 + m] = best[r];
        ri[tl * 17 + m] = bi[r];
    }
    __syncthreads();

    if (tid < 64) {
        const int t = t0 + tid;
        float b = rb[tid * 17]; int ix = ri[tid * 17];
#pragma unroll
        for (int j = 1; j < 16; ++j) {
            float v = rb[tid * 17 + j]; int iv = ri[tid * 17 + j];
            if (v < b || (v == b && iv < ix)) { b = v; ix = iv; }
        }
        if (t < 2040) {
            const float4* ev = (const float4*)(emb + (long)ix * 80);
            const bool hasq = (t < 2016);
            const float4* qv = hasq
                ? (const float4*)(enc_q + ((long)n * 504 + (t % 504)) * 80) : nullptr;
            float p0 = b_lin[0], p1 = b_lin[1];
#pragma unroll
            for (int i = 0; i < 20; ++i) {
                float4 e4 = ev[i];
                float4 q4 = hasq ? qv[i] : make_float4(0.f, 0.f, 0.f, 0.f);
                float4 w0 = *(const float4*)(w_lin + 4 * i);
                float4 w1 = *(const float4*)(w_lin + 80 + 4 * i);
                float sx = e4.x + q4.x, sy = e4.y + q4.y;
                float sz = e4.z + q4.z, sw = e4.w + q4.w;
                p0 = fmaf(sx, w0.x, p0); p1 = fmaf(sx, w1.x, p1);
                p0 = fmaf(sy, w0.y, p0); p1 = fmaf(sy, w1.y, p1);
                p0 = fmaf(sz, w0.z, p0); p1 = fmaf(sz, w1.z, p1);
                p0 = fmaf(sw, w0.w, p0); p1 = fmaf(sw, w1.w, p1);
            }
            long o = ((long)n * 2040 + t) * 2;
            pred[o]     = fast_tanh(p0);
            pred[o + 1] = fast_tanh(p1);
        }
    }
}

// ============================================================================
__global__ __launch_bounds__(256) void max_red(const float* __restrict__ pred,
                                               float* __restrict__ out)
{
    __shared__ float s0[256], s1[256];
    const int n = blockIdx.x, tid = threadIdx.x;
    float m0 = -1e30f, m1 = -1e30f;
    for (int t = tid; t < 2040; t += 256) {
        long o = ((long)n * 2040 + t) * 2;
        m0 = fmaxf(m0, pred[o]);
        m1 = fmaxf(m1, pred[o + 1]);
    }
    s0[tid] = m0; s1[tid] = m1;
    __syncthreads();
    for (int st = 128; st > 0; st >>= 1) {
        if (tid < st) {
            s0[tid] = fmaxf(s0[tid], s0[tid + st]);
            s1[tid] = fmaxf(s1[tid], s1[tid + st]);
        }
        __syncthreads();
    }
    if (tid == 0) { out[n * 2] = s0[0]; out[n * 2 + 1] = s1[0]; }
}

// ============================================================================
extern "C" void kernel_launch(void* const* d_in, const int* in_sizes, int n_in,
                              void* d_out, int out_size, void* d_ws, size_t ws_size,
                              hipStream_t stream)
{
    const float* search = (const float*)d_in[0];
    const float* query  = (const float*)d_in[1];
    const float* w_wide = (const float*)d_in[2];
    const float* b_wide = (const float*)d_in[3];
    const float* w_1x1  = (const float*)d_in[4];
    const float* b_1x1  = (const float*)d_in[5];
    const float* w_f0   = (const float*)d_in[6];
    const float* b_f0   = (const float*)d_in[7];
    const float* w_f1   = (const float*)d_in[8];
    const float* b_f1   = (const float*)d_in[9];
    const float* emb    = (const float*)d_in[10];
    const float* w_lin  = (const float*)d_in[11];
    const float* b_lin  = (const float*)d_in[12];
    float* out = (float*)d_out;
    float* ws  = (float*)d_ws;

    // fp32 flow: L0: in->A/QA; L1: A->B/QB; L2: B->C/QC; L3: C->B(encS)/QB(encQ);
    // vq: pred->C.
    float* A  = ws;                 // 5,241,600
    float* B  = A  + 5241600;       // 2,618,880
    float* C  = B  + 2618880;       // 2,618,880
    float* QA = C  + 2618880;       // 1,309,440
    float* QB = QA + 1309440;       //   652,800
    float* QC = QB + 652800;        //   652,800
    unsigned short* WWp = (unsigned short*)(QC + 652800);
    unsigned short* W1p = WWp + 204800;        // 4 x 80 x 96
    unsigned short* F0p = W1p + 30720;         // 80 x 96
    unsigned short* F1p = F0p + 7680;
    unsigned short* EMp = F1p + 7680;          // 512 x 80
    float* e2b = (float*)(EMp + 40960);        // 512

    const dim3 blk(320);
    auto nb = [](int T) { return (T + 31) / 32; };

    pack_all<<<dim3(1142), dim3(256), 0, stream>>>(w_wide, w_1x1, w_f0, w_f1, emb,
                                                   WWp, W1p, F0p, F1p, EMp, e2b);

    enc_layer<2, false, false><<<dim3(nb(4095) + nb(1023), NBATCH), blk, 0, stream>>>(
        search, query, WWp, b_wide, W1p, b_1x1, nullptr, nullptr, nullptr, nullptr,
        A, QA, 8192, 4095, 2048, 1023, nb(4095));
    enc_layer<2, true, false><<<dim3(nb(2046) + nb(510), NBATCH), blk, 0, stream>>>(
        A, QA, WWp + 51200, b_wide + 160, W1p + 7680, b_1x1 + 80,
        nullptr, nullptr, nullptr, nullptr,
        B, QB, 4095, 2046, 1023, 510, nb(2046));
    enc_layer<1, true, false><<<dim3(nb(2043) + nb(507), NBATCH), blk, 0, stream>>>(
        B, QB, WWp + 102400, b_wide + 320, W1p + 15360, b_1x1 + 160,
        nullptr, nullptr, nullptr, nullptr,
        C, QC, 2046, 2043, 510, 507, nb(2043));
    enc_layer<1, true, true><<<dim3(nb(2040) + nb(504), NBATCH), blk, 0, stream>>>(
        C, QC, WWp + 153600, b_wide + 480, W1p + 23040, b_1x1 + 240,
        F0p, b_f0, F1p, b_f1,
        B, QB, 2043, 2040, 507, 504, nb(2040));

    vq_mfma<<<dim3(32, NBATCH), dim3(256), 0, stream>>>(B, QB, EMp, emb, e2b,
                                                        w_lin, b_lin, C);
    max_red<<<dim3(NBATCH), dim3(256), 0, stream>>>(C, out);
}